// Round 2
// baseline (1024.949 us; speedup 1.0000x reference)
//
#include <hip/hip_runtime.h>
#include <stdint.h>

typedef _Float16 f16;
typedef _Float16 f16x2 __attribute__((ext_vector_type(2)));
typedef _Float16 f16x8 __attribute__((ext_vector_type(8)));
typedef float f32x4 __attribute__((ext_vector_type(4)));

#define SEQ   512
#define BATCH 128
#define DIM   512
#define HID   256
#define G4    1024
#define MTOT  (BATCH*SEQ)

typedef const __attribute__((address_space(1))) void* gas1p;
typedef __attribute__((address_space(3))) void* las3p;

__device__ __forceinline__ uint32_t pk2(float a, float b){
  return __builtin_bit_cast(uint32_t, __builtin_amdgcn_cvt_pkrtz(a, b));
}

__device__ __forceinline__ float fdot2u(uint32_t a, uint32_t b, float c){
#if __has_builtin(__builtin_amdgcn_fdot2)
  f16x2 A = __builtin_bit_cast(f16x2, a);
  f16x2 B = __builtin_bit_cast(f16x2, b);
  return __builtin_amdgcn_fdot2(A, B, c, false);
#else
  f16x2 A = __builtin_bit_cast(f16x2, a);
  f16x2 B = __builtin_bit_cast(f16x2, b);
  return c + (float)A.x*(float)B.x + (float)A.y*(float)B.y;
#endif
}

__device__ __forceinline__ float sigm(float x){
  return __builtin_amdgcn_rcpf(1.0f + __expf(-x));
}
__device__ __forceinline__ float tanh_(float x){
  return 1.0f - 2.0f*__builtin_amdgcn_rcpf(__expf(2.0f*x) + 1.0f);
}

// ---------------- phase 0: fp32 -> f16 convert (vectorized, 8 elems/thread) ----
__global__ void __launch_bounds__(256) cvt_f16_kernel(const float* __restrict__ in,
                                                      f16* __restrict__ out, int n8){
  int i = blockIdx.x*blockDim.x + threadIdx.x;
  if (i >= n8) return;
  const float4* p = (const float4*)in;
  float4 a = p[2*i], b = p[2*i+1];
  uint4 r;
  r.x = pk2(a.x, a.y); r.y = pk2(a.z, a.w);
  r.z = pk2(b.x, b.y); r.w = pk2(b.z, b.w);
  ((uint4*)out)[i] = r;
}

// ---------------- phase 1: xg[m][g] = A[m][:] . W[g][:] + bias[g]  (f16 MFMA) --
#define BM 128
#define BN 128
#define BK 64

__global__ void __launch_bounds__(256) gemm_xg_kernel(const f16* __restrict__ A,
                                                      const f16* __restrict__ Bm,
                                                      const float* __restrict__ bih,
                                                      const float* __restrict__ bhh,
                                                      f16* __restrict__ C){
  __shared__ __align__(16) f16 ldsA[BM*BK];
  __shared__ __align__(16) f16 ldsB[BN*BK];
  const int tid  = threadIdx.x;
  const int wave = tid >> 6;
  const int lane = tid & 63;
  const int bid  = blockIdx.x;
  const int nt   = bid & 7;         // 8 n-tiles (N=1024)
  const int mt   = bid >> 3;
  const long m0  = (long)mt * BM;
  const int n0   = nt * BN;
  const int wm   = wave >> 1, wn = wave & 1;   // 2x2 waves, 64x64 each
  const int lrow = lane >> 3;
  const int lk   = (lane & 7) * 8;

  f32x4 acc[4][4];
  #pragma unroll
  for (int i=0;i<4;++i)
    #pragma unroll
    for (int j=0;j<4;++j) acc[i][j] = (f32x4){0.f,0.f,0.f,0.f};

  auto ldsAq = (__attribute__((address_space(3))) char*)ldsA;
  auto ldsBq = (__attribute__((address_space(3))) char*)ldsB;

  for (int kt = 0; kt < DIM/BK; ++kt){
    const int k0 = kt*BK;
    __syncthreads();
    #pragma unroll
    for (int i = 0; i < 4; ++i){
      const int seg = wave*4 + i;              // 16 segments of 1024 B each
      const f16* ga = A  + (m0 + seg*8 + lrow)*DIM + (k0 + lk);
      const f16* gb = Bm + (long)(n0 + seg*8 + lrow)*DIM + (k0 + lk);
      __builtin_amdgcn_global_load_lds((gas1p)ga, (las3p)(ldsAq + seg*1024), 16, 0, 0);
      __builtin_amdgcn_global_load_lds((gas1p)gb, (las3p)(ldsBq + seg*1024), 16, 0, 0);
    }
    __syncthreads();
    #pragma unroll
    for (int kk = 0; kk < 2; ++kk){
      f16x8 af[4], bf[4];
      const int kb = kk*32 + (lane>>4)*8;
      #pragma unroll
      for (int mi=0; mi<4; ++mi){
        af[mi] = *(const f16x8*)(ldsA + (wm*64 + mi*16 + (lane&15))*BK + kb);
        bf[mi] = *(const f16x8*)(ldsB + (wn*64 + mi*16 + (lane&15))*BK + kb);
      }
      #pragma unroll
      for (int mi=0;mi<4;++mi)
        #pragma unroll
        for (int ni=0;ni<4;++ni)
          acc[mi][ni] = __builtin_amdgcn_mfma_f32_16x16x32_f16(af[mi], bf[ni], acc[mi][ni], 0,0,0);
    }
  }
  float bias[4];
  #pragma unroll
  for (int ni=0;ni<4;++ni){
    int col = n0 + wn*64 + ni*16 + (lane&15);
    bias[ni] = bih[col] + bhh[col];
  }
  #pragma unroll
  for (int mi=0;mi<4;++mi){
    #pragma unroll
    for (int ni=0;ni<4;++ni){
      int col = n0 + wn*64 + ni*16 + (lane&15);
      #pragma unroll
      for (int r=0;r<4;++r){
        long row = m0 + wm*64 + mi*16 + (lane>>4)*4 + r;
        C[row*G4 + col] = (f16)(acc[mi][ni][r] + bias[ni]);
      }
    }
  }
}

// ---------------- phase 2: sequential LSTM + fused FC head ---------------------
// 128 blocks (1 per batch row) x 512 threads. Thread t computes gate rows t and
// t+512. W_hh k in [64,256) lives in VGPRs (f16 pairs), k in [0,64) in LDS.
__global__ void __launch_bounds__(512, 2) lstm_kernel(const f16* __restrict__ xg,
                                                      const float* __restrict__ Whh,
                                                      const float* __restrict__ fcw,
                                                      const float* __restrict__ fcb,
                                                      float* __restrict__ out){
  extern __shared__ __align__(16) char smem[];
  uint4* Wl4 = (uint4*)smem;                   // [8][1024] quads (k 0..63): 128 KiB
  f16*   h1  = (f16*)(smem + 131072);          // h state, 256 f16
  float* ig  = (float*)(smem + 131072 + 512);  // i*g exchange, 256 f32
  const int t  = threadIdx.x;
  const int b  = blockIdx.x;
  const int g0 = t, g1 = t + 512;

  // ---- preload register weights: k in [64,256) for both gates (f16 pairs)
  uint32_t w0[96], w1[96];
  #pragma unroll
  for (int q = 0; q < 48; ++q){
    float4 v = *(const float4*)(Whh + g0*HID + 64 + 4*q);
    w0[2*q] = pk2(v.x, v.y); w0[2*q+1] = pk2(v.z, v.w);
  }
  #pragma unroll
  for (int q = 0; q < 48; ++q){
    float4 v = *(const float4*)(Whh + g1*HID + 64 + 4*q);
    w1[2*q] = pk2(v.x, v.y); w1[2*q+1] = pk2(v.z, v.w);
  }
  // ---- cooperative LDS weights: k in [0,64) for all 1024 gates
  for (int idx = t; idx < 8*1024; idx += 512){
    int ko = idx >> 10, g = idx & 1023;
    const float* wr = Whh + g*HID + 8*ko;
    float4 v0 = *(const float4*)(wr);
    float4 v1 = *(const float4*)(wr + 4);
    Wl4[idx] = make_uint4(pk2(v0.x,v0.y), pk2(v0.z,v0.w), pk2(v1.x,v1.y), pk2(v1.z,v1.w));
  }
  float c = 0.f, hreg = 0.f;
  if (t < 256) h1[t] = (f16)0.f;
  __syncthreads();

  const f16* xrow = xg + (long)b * SEQ * G4;
  f16 pa = xrow[g0], pb = xrow[g1];            // step-0 preload

  for (int ts = 0; ts < SEQ; ++ts){
    float acc0 = (float)pa, acc1 = (float)pb;
    if (ts + 1 < SEQ){                         // prefetch next step's xg
      pa = xrow[(ts+1)*G4 + g0];
      pb = xrow[(ts+1)*G4 + g1];
    }
    const uint4* h4 = (const uint4*)h1;        // 32 x (8 f16) broadcast reads
    #pragma unroll
    for (int q = 0; q < 8; ++q){               // LDS-resident weights: k 0..63
      uint4 hv  = h4[q];
      uint4 wv0 = Wl4[q*1024 + g0];
      uint4 wv1 = Wl4[q*1024 + g1];
      acc0 = fdot2u(wv0.x, hv.x, acc0);
      acc0 = fdot2u(wv0.y, hv.y, acc0);
      acc0 = fdot2u(wv0.z, hv.z, acc0);
      acc0 = fdot2u(wv0.w, hv.w, acc0);
      acc1 = fdot2u(wv1.x, hv.x, acc1);
      acc1 = fdot2u(wv1.y, hv.y, acc1);
      acc1 = fdot2u(wv1.z, hv.z, acc1);
      acc1 = fdot2u(wv1.w, hv.w, acc1);
    }
    #pragma unroll
    for (int q = 8; q < 32; ++q){              // register weights: k 64..255
      uint4 hv = h4[q];
      const int base = (q-8)*4;
      acc0 = fdot2u(w0[base+0], hv.x, acc0);
      acc0 = fdot2u(w0[base+1], hv.y, acc0);
      acc0 = fdot2u(w0[base+2], hv.z, acc0);
      acc0 = fdot2u(w0[base+3], hv.w, acc0);
      acc1 = fdot2u(w1[base+0], hv.x, acc1);
      acc1 = fdot2u(w1[base+1], hv.y, acc1);
      acc1 = fdot2u(w1[base+2], hv.z, acc1);
      acc1 = fdot2u(w1[base+3], hv.w, acc1);
    }
    // t<256: acc0=i[t], acc1=g[t].  t>=256: acc0=f[j], acc1=o[j], j=t-256.
    if (t < 256) ig[t] = sigm(acc0) * tanh_(acc1);
    __syncthreads();
    if (t >= 256){
      int j = t - 256;
      c    = sigm(acc0)*c + ig[j];
      hreg = sigm(acc1) * tanh_(c);
      h1[j] = (f16)hreg;
    }
    __syncthreads();
  }
  // ---- fused FC head: logit[b] = h . fc_w + fc_b
  if (t >= 256) ig[t-256] = hreg;              // reuse ig as fp32 h buffer
  __syncthreads();
  if (t < 64){
    float s = 0.f;
    #pragma unroll
    for (int q=0;q<4;++q){ int j = t + 64*q; s += ig[j]*fcw[j]; }
    #pragma unroll
    for (int off=32; off; off>>=1) s += __shfl_down(s, off);
    if (t==0) out[b] = s + fcb[0];
  }
}

extern "C" void kernel_launch(void* const* d_in, const int* in_sizes, int n_in,
                              void* d_out, int out_size, void* d_ws, size_t ws_size,
                              hipStream_t stream) {
  const float* x   = (const float*)d_in[0];
  const float* Wih = (const float*)d_in[1];
  const float* Whh = (const float*)d_in[2];
  const float* bih = (const float*)d_in[3];
  const float* bhh = (const float*)d_in[4];
  const float* fcw = (const float*)d_in[5];
  const float* fcb = (const float*)d_in[6];
  float* out = (float*)d_out;

  char* ws = (char*)d_ws;
  f16* xh = (f16*)ws;                               //  67,108,864 B
  f16* Wh = (f16*)(ws + 67108864);                  //   1,048,576 B
  f16* xg = (f16*)(ws + 67108864 + 1048576);        // 134,217,728 B  (total ~202 MB)

  // phase 0: converts
  cvt_f16_kernel<<<16384, 256, 0, stream>>>(x,   xh, 33554432/8);
  cvt_f16_kernel<<<256,   256, 0, stream>>>(Wih, Wh, 524288/8);
  // phase 1: input-projection GEMM (+bias), f16 MFMA
  gemm_xg_kernel<<<4096, 256, 0, stream>>>(xh, Wh, bih, bhh, xg);
  // phase 2: sequential recurrence + FC head
  (void)hipFuncSetAttribute(reinterpret_cast<const void*>(lstm_kernel),
                            hipFuncAttributeMaxDynamicSharedMemorySize, 132608);
  lstm_kernel<<<BATCH, 512, 132608, stream>>>(xg, Whh, fcw, fcb, out);
}